// Round 1
// baseline (2617.447 us; speedup 1.0000x reference)
//
#include <hip/hip_runtime.h>
#include <hip/hip_bf16.h>
#include <stdint.h>

#define BL    4096      // BATCH*SEQ
#define DM    768       // d_model
#define DI    1536      // d_inner
#define DS    16        // d_state
#define DCONV 4
#define DTR   48        // dt_rank
#define NL    2
#define SEQL  2048
#define BATCH 2
#define VOC   32000

typedef __bf16 bf16_t;
typedef __bf16 bf16x8 __attribute__((ext_vector_type(8)));
typedef __bf16 bf16x4 __attribute__((ext_vector_type(4)));
typedef float  f32x4  __attribute__((ext_vector_type(4)));

__device__ __forceinline__ float sigmoidf_(float x) { return 1.f / (1.f + __expf(-x)); }

// ---------------- embedding gather ----------------
__global__ __launch_bounds__(256) void k_embed(const int* __restrict__ x,
                                               const float* __restrict__ emb,
                                               float* __restrict__ h) {
  int row = blockIdx.x;
  int tok = x[row];
  const float* e = emb + (size_t)tok * DM;
  float* hr = h + (size_t)row * DM;
  for (int c = threadIdx.x; c < DM; c += 256) hr[c] = e[c];
}

// ---------------- f32 -> bf16, vectorized (n % 4 == 0) ----------------
__global__ __launch_bounds__(256) void k_cvt(const float* __restrict__ src,
                                             bf16_t* __restrict__ dst, long n4) {
  long i = (long)blockIdx.x * 256 + threadIdx.x;
  if (i >= n4) return;
  float4 v = ((const float4*)src)[i];
  bf16x4 o;
  o[0] = (bf16_t)v.x; o[1] = (bf16_t)v.y; o[2] = (bf16_t)v.z; o[3] = (bf16_t)v.w;
  ((bf16x4*)dst)[i] = o;
}

// ---------------- f32 -> bf16 with zero padding (R x C, ld srcLd -> Rpad x Cpad) ----
__global__ __launch_bounds__(256) void k_cvt_pad(const float* __restrict__ src,
                                                 bf16_t* __restrict__ dst,
                                                 int R, int C, int srcLd, int Cpad,
                                                 long total) {
  long i = (long)blockIdx.x * 256 + threadIdx.x;
  if (i >= total) return;
  int r = (int)(i / Cpad), c = (int)(i % Cpad);
  float v = (r < R && c < C) ? src[(size_t)r * srcLd + c] : 0.f;
  dst[i] = (bf16_t)v;
}

// ---------------- causal depthwise conv (w=4) + bias + silu ----------------
__global__ __launch_bounds__(256) void k_conv(const float* __restrict__ xz,
                                              const float* __restrict__ cw,
                                              const float* __restrict__ cb,
                                              float* __restrict__ uc, long total) {
  long i = (long)blockIdx.x * 256 + threadIdx.x;
  if (i >= total) return;
  int d = (int)(i % DI);
  long row = i / DI;
  int l = (int)(row % SEQL);
  const float* w = cw + (size_t)d * DCONV;
  float s = cb[d];
#pragma unroll
  for (int j = 0; j < DCONV; j++) {
    int lj = l - (DCONV - 1) + j;
    if (lj >= 0) s += xz[(row - (DCONV - 1) + j) * (2 * DI) + d] * w[j];
  }
  uc[i] = s * sigmoidf_(s);
}

// ---------------- selective scan: 16 lanes per (b,d) channel ----------------
__global__ __launch_bounds__(256) void k_scan(const float* __restrict__ dt,
                                              const float* __restrict__ uc,
                                              const float* __restrict__ xdbl,
                                              const float* __restrict__ A_log,
                                              float* __restrict__ ys) {
  int gi = blockIdx.x * 256 + threadIdx.x;
  int g = gi >> 4;            // channel index (b*DI + d)
  int s = gi & 15;            // state index
  int b = g / DI;
  int d = g - b * DI;
  float a = -__expf(A_log[d * DS + s]);
  const float* dtp = dt + (long)b * SEQL * DI + d;
  const float* ucp = uc + (long)b * SEQL * DI + d;
  const float* Bp = xdbl + (long)b * SEQL * 80 + DTR + s;
  const float* Cp = Bp + DS;
  float* yp = ys + (long)b * SEQL * DI + d;
  float h = 0.f;
  for (int l = 0; l < SEQL; l++) {
    float dtv = dtp[(long)l * DI];
    float uv  = ucp[(long)l * DI];
    float Bv  = Bp[(long)l * 80];
    float Cv  = Cp[(long)l * 80];
    h = __expf(dtv * a) * h + (dtv * uv) * Bv;
    float y = h * Cv;
    y += __shfl_xor(y, 1);
    y += __shfl_xor(y, 2);
    y += __shfl_xor(y, 4);
    y += __shfl_xor(y, 8);
    if (s == 0) yp[(long)l * DI] = y;
  }
}

// ---------------- skip + gate, write bf16 A-operand ----------------
__global__ __launch_bounds__(256) void k_gate(const float* __restrict__ ys,
                                              const float* __restrict__ uc,
                                              const float* __restrict__ xz,
                                              const float* __restrict__ Dsk,
                                              bf16_t* __restrict__ o, long total) {
  long i = (long)blockIdx.x * 256 + threadIdx.x;
  if (i >= total) return;
  int d = (int)(i % DI);
  long row = i / DI;
  float y = ys[i] + uc[i] * Dsk[d];
  float z = xz[row * (2 * DI) + DI + d];
  o[i] = (bf16_t)(y * z * sigmoidf_(z));
}

// ---------------- final LayerNorm, write bf16 A-operand ----------------
__global__ __launch_bounds__(256) void k_ln(const float* __restrict__ h,
                                            const float* __restrict__ g,
                                            const float* __restrict__ bta,
                                            bf16_t* __restrict__ o) {
  __shared__ float sm[4];
  int row = blockIdx.x;
  int t = threadIdx.x;
  const float* hr = h + (long)row * DM;
  float v0 = hr[t], v1 = hr[t + 256], v2 = hr[t + 512];
  float s = v0 + v1 + v2;
#pragma unroll
  for (int off = 32; off > 0; off >>= 1) s += __shfl_down(s, off);
  if ((t & 63) == 0) sm[t >> 6] = s;
  __syncthreads();
  float mu = (sm[0] + sm[1] + sm[2] + sm[3]) * (1.f / DM);
  __syncthreads();
  float d0 = v0 - mu, d1 = v1 - mu, d2 = v2 - mu;
  float q = d0 * d0 + d1 * d1 + d2 * d2;
#pragma unroll
  for (int off = 32; off > 0; off >>= 1) q += __shfl_down(q, off);
  if ((t & 63) == 0) sm[t >> 6] = q;
  __syncthreads();
  float var = (sm[0] + sm[1] + sm[2] + sm[3]) * (1.f / DM);
  float rs = rsqrtf(var + 1e-5f);
  bf16_t* orow = o + (long)row * DM;
  orow[t]       = (bf16_t)(d0 * rs * g[t]       + bta[t]);
  orow[t + 256] = (bf16_t)(d1 * rs * g[t + 256] + bta[t + 256]);
  orow[t + 512] = (bf16_t)(d2 * rs * g[t + 512] + bta[t + 512]);
}

// ---------------- bf16 MFMA GEMM, NT: C(MxN) = A(MxK) * W(NxK)^T ----------------
// EPI: 0 = plain, 1 = +bias[n], 2 = += C (residual), 3 = softplus(acc + bias[n])
__device__ __forceinline__ void stage16(const bf16_t* gp, bf16_t* lp) {
  __builtin_amdgcn_global_load_lds(
      (const __attribute__((address_space(1))) uint32_t*)gp,
      (__attribute__((address_space(3))) uint32_t*)lp, 16, 0, 0);
}

template <int EPI>
__global__ __launch_bounds__(256) void k_gemm(const bf16_t* __restrict__ A,
                                              const bf16_t* __restrict__ W,
                                              float* __restrict__ C,
                                              const float* __restrict__ bias,
                                              int M, int N, int K, int ldc) {
  __shared__ bf16_t lA[128 * 32];
  __shared__ bf16_t lB[128 * 32];
  const int tid = threadIdx.x;
  const int lane = tid & 63;
  const int wv = tid >> 6;
  const int wm = wv >> 1, wn = wv & 1;
  const long m0 = (long)blockIdx.y * 128;
  const long n0 = (long)blockIdx.x * 128;
  const int r0 = tid >> 2;             // staging row 0..63
  const int c8 = (tid & 3) * 8;        // staging col (elems)
  const int fr = lane & 15;            // fragment row
  const int kq = lane >> 4;            // k-quarter

  f32x4 acc[4][4];
#pragma unroll
  for (int i = 0; i < 4; i++)
#pragma unroll
    for (int j = 0; j < 4; j++) acc[i][j] = (f32x4){0.f, 0.f, 0.f, 0.f};

  const bf16_t* Ab = A + (m0 + r0) * (long)K + c8;
  const bf16_t* Wb = W + (n0 + r0) * (long)K + c8;
  bf16_t* lAp = lA + r0 * 32 + c8;
  bf16_t* lBp = lB + r0 * 32 + c8;
  const long s64K = 64L * K;

  for (int k0 = 0; k0 < K; k0 += 32) {
    __syncthreads();
    stage16(Ab + k0, lAp);
    stage16(Ab + k0 + s64K, lAp + 64 * 32);
    stage16(Wb + k0, lBp);
    stage16(Wb + k0 + s64K, lBp + 64 * 32);
    __syncthreads();  // compiler emits vmcnt(0) drain before barrier
    bf16x8 af[4], bfv[4];
#pragma unroll
    for (int f = 0; f < 4; f++)
      af[f] = *(const bf16x8*)&lA[(wm * 64 + f * 16 + fr) * 32 + kq * 8];
#pragma unroll
    for (int f = 0; f < 4; f++)
      bfv[f] = *(const bf16x8*)&lB[(wn * 64 + f * 16 + fr) * 32 + kq * 8];
#pragma unroll
    for (int fm = 0; fm < 4; fm++)
#pragma unroll
      for (int fn = 0; fn < 4; fn++)
        acc[fm][fn] = __builtin_amdgcn_mfma_f32_16x16x32_bf16(af[fm], bfv[fn],
                                                              acc[fm][fn], 0, 0, 0);
  }

  const int r4 = (lane >> 4) * 4;
  const int cc = lane & 15;
#pragma unroll
  for (int fm = 0; fm < 4; fm++) {
    long rowb = m0 + wm * 64 + fm * 16 + r4;
#pragma unroll
    for (int fn = 0; fn < 4; fn++) {
      long col = n0 + wn * 64 + fn * 16 + cc;
      if (col < N) {
        float bv = (EPI == 1 || EPI == 3) ? bias[col] : 0.f;
#pragma unroll
        for (int r = 0; r < 4; r++) {
          long row = rowb + r;
          float v = acc[fm][fn][r];
          if (EPI == 1) v += bv;
          else if (EPI == 3) { v += bv; v = (v > 20.f) ? v : log1pf(__expf(v)); }
          else if (EPI == 2) v += C[row * (long)ldc + col];
          C[row * (long)ldc + col] = v;
        }
      }
    }
  }
}

static inline int cdiv_l(long a, long b) { return (int)((a + b - 1) / b); }

extern "C" void kernel_launch(void* const* d_in, const int* in_sizes, int n_in,
                              void* d_out, int out_size, void* d_ws, size_t ws_size,
                              hipStream_t stream) {
  (void)in_sizes; (void)n_in; (void)out_size; (void)ws_size;
  const int*   x      = (const int*)  d_in[0];
  const float* emb    = (const float*)d_in[1];
  const float* W_in   = (const float*)d_in[2];
  const float* conv_w = (const float*)d_in[3];
  const float* conv_b = (const float*)d_in[4];
  const float* W_x    = (const float*)d_in[5];
  const float* W_dt   = (const float*)d_in[6];
  const float* b_dt   = (const float*)d_in[7];
  const float* A_log  = (const float*)d_in[8];
  const float* D_skip = (const float*)d_in[9];
  const float* W_out  = (const float*)d_in[10];
  const float* ln_g   = (const float*)d_in[11];
  const float* ln_b   = (const float*)d_in[12];
  const float* head_w = (const float*)d_in[13];
  const float* head_b = (const float*)d_in[14];
  float* out = (float*)d_out;

  // bf16 staging in d_ws (must be live during head GEMM): 61.8 MB
  char* ws = (char*)d_ws;
  bf16_t* abuf = (bf16_t*)ws;                               // up to BL*DI bf16
  bf16_t* wbuf = (bf16_t*)(ws + (size_t)BL * DI * 2);       // up to VOC*DM bf16

  // f32 intermediates overlaid into d_out (131M floats; all dead before head GEMM)
  float* xz   = out;                         // BL * 2*DI
  float* uc   = xz   + (size_t)BL * 2 * DI;  // BL * DI
  float* xdbl = uc   + (size_t)BL * DI;      // BL * 80
  float* dtb  = xdbl + (size_t)BL * 80;      // BL * DI
  float* ysb  = dtb  + (size_t)BL * DI;      // BL * DI
  float* h    = ysb  + (size_t)BL * DI;      // BL * DM   (ends at 34.9M floats)

  k_embed<<<BL, 256, 0, stream>>>(x, emb, h);

  for (int l = 0; l < NL; ++l) {
    // ---- in_proj: xz = h @ W_in^T  (4096 x 3072, K=768) ----
    k_cvt<<<cdiv_l((long)BL * DM / 4, 256), 256, 0, stream>>>(h, abuf, (long)BL * DM / 4);
    k_cvt<<<cdiv_l((long)2 * DI * DM / 4, 256), 256, 0, stream>>>(
        W_in + (size_t)l * 2 * DI * DM, wbuf, (long)2 * DI * DM / 4);
    k_gemm<0><<<dim3(2 * DI / 128, BL / 128), 256, 0, stream>>>(
        abuf, wbuf, xz, nullptr, BL, 2 * DI, DM, 2 * DI);
    // ---- causal dw-conv + silu ----
    k_conv<<<cdiv_l((long)BL * DI, 256), 256, 0, stream>>>(
        xz, conv_w + (size_t)l * DI * DCONV, conv_b + (size_t)l * DI, uc, (long)BL * DI);
    // ---- x_proj: xdbl = uc @ W_x^T  (4096 x 80, K=1536; W padded to 128 rows) ----
    k_cvt<<<cdiv_l((long)BL * DI / 4, 256), 256, 0, stream>>>(uc, abuf, (long)BL * DI / 4);
    k_cvt_pad<<<cdiv_l(128L * DI, 256), 256, 0, stream>>>(
        W_x + (size_t)l * 80 * DI, wbuf, 80, DI, DI, DI, 128L * DI);
    k_gemm<0><<<dim3(1, BL / 128), 256, 0, stream>>>(
        abuf, wbuf, xdbl, nullptr, BL, 80, DI, 80);
    // ---- dt = softplus(dtlin @ W_dt^T + b_dt)  (K=48 padded to 64) ----
    k_cvt_pad<<<cdiv_l((long)BL * 64, 256), 256, 0, stream>>>(
        xdbl, abuf, BL, DTR, 80, 64, (long)BL * 64);
    k_cvt_pad<<<cdiv_l((long)DI * 64, 256), 256, 0, stream>>>(
        W_dt + (size_t)l * DI * DTR, wbuf, DI, DTR, DTR, 64, (long)DI * 64);
    k_gemm<3><<<dim3(DI / 128, BL / 128), 256, 0, stream>>>(
        abuf, wbuf, dtb, b_dt + (size_t)l * DI, BL, DI, 64, DI);
    // ---- selective scan ----
    k_scan<<<(BATCH * DI * DS) / 256, 256, 0, stream>>>(
        dtb, uc, xdbl, A_log + (size_t)l * DI * DS, ysb);
    // ---- skip + gate -> bf16 ----
    k_gate<<<cdiv_l((long)BL * DI, 256), 256, 0, stream>>>(
        ysb, uc, xz, D_skip + (size_t)l * DI, abuf, (long)BL * DI);
    // ---- out_proj + residual: h += y @ W_out^T  (4096 x 768, K=1536) ----
    k_cvt<<<cdiv_l((long)DM * DI / 4, 256), 256, 0, stream>>>(
        W_out + (size_t)l * DM * DI, wbuf, (long)DM * DI / 4);
    k_gemm<2><<<dim3(DM / 128, BL / 128), 256, 0, stream>>>(
        abuf, wbuf, h, nullptr, BL, DM, DI, DM);
  }

  // ---- final LN -> bf16, head GEMM + bias ----
  k_ln<<<BL, 256, 0, stream>>>(h, ln_g, ln_b, abuf);
  k_cvt<<<cdiv_l((long)VOC * DM / 4, 256), 256, 0, stream>>>(head_w, wbuf, (long)VOC * DM / 4);
  k_gemm<1><<<dim3(VOC / 128, BL / 128), 256, 0, stream>>>(
      abuf, wbuf, out, head_b, BL, VOC, DM, VOC);
}

// Round 2
// 1122.830 us; speedup vs baseline: 2.3311x; 2.3311x over previous
//
#include <hip/hip_runtime.h>
#include <hip/hip_bf16.h>
#include <stdint.h>

#define BL    4096      // BATCH*SEQ
#define DM    768       // d_model
#define DI    1536      // d_inner
#define DS    16        // d_state
#define DCONV 4
#define DTR   48        // dt_rank
#define NL    2
#define SEQL  2048
#define BATCH 2
#define VOC   32000
#define NCH   32        // scan chunks
#define CT    64        // steps per chunk (SEQL/NCH)

typedef __bf16 bf16_t;
typedef __bf16 bf16x8 __attribute__((ext_vector_type(8)));
typedef __bf16 bf16x4 __attribute__((ext_vector_type(4)));
typedef float  f32x4  __attribute__((ext_vector_type(4)));

__device__ __forceinline__ float sigmoidf_(float x) { return 1.f / (1.f + __expf(-x)); }

// ---------------- embedding gather ----------------
__global__ __launch_bounds__(256) void k_embed(const int* __restrict__ x,
                                               const float* __restrict__ emb,
                                               float* __restrict__ h) {
  int row = blockIdx.x;
  int tok = x[row];
  const float* e = emb + (size_t)tok * DM;
  float* hr = h + (size_t)row * DM;
  for (int c = threadIdx.x; c < DM; c += 256) hr[c] = e[c];
}

// ---------------- f32 -> bf16, vectorized (n % 4 == 0) ----------------
__global__ __launch_bounds__(256) void k_cvt(const float* __restrict__ src,
                                             bf16_t* __restrict__ dst, long n4) {
  long i = (long)blockIdx.x * 256 + threadIdx.x;
  if (i >= n4) return;
  float4 v = ((const float4*)src)[i];
  bf16x4 o;
  o[0] = (bf16_t)v.x; o[1] = (bf16_t)v.y; o[2] = (bf16_t)v.z; o[3] = (bf16_t)v.w;
  ((bf16x4*)dst)[i] = o;
}

// ---------------- f32 -> bf16 with zero padding (R x C, ld srcLd -> Rpad x Cpad) ----
__global__ __launch_bounds__(256) void k_cvt_pad(const float* __restrict__ src,
                                                 bf16_t* __restrict__ dst,
                                                 int R, int C, int srcLd, int Cpad,
                                                 long total) {
  long i = (long)blockIdx.x * 256 + threadIdx.x;
  if (i >= total) return;
  int r = (int)(i / Cpad), c = (int)(i % Cpad);
  float v = (r < R && c < C) ? src[(size_t)r * srcLd + c] : 0.f;
  dst[i] = (bf16_t)v;
}

// ---------------- causal depthwise conv (w=4) + bias + silu ----------------
__global__ __launch_bounds__(256) void k_conv(const float* __restrict__ xz,
                                              const float* __restrict__ cw,
                                              const float* __restrict__ cb,
                                              float* __restrict__ uc, long total) {
  long i = (long)blockIdx.x * 256 + threadIdx.x;
  if (i >= total) return;
  int d = (int)(i % DI);
  long row = i / DI;
  int l = (int)(row % SEQL);
  const float* w = cw + (size_t)d * DCONV;
  float s = cb[d];
#pragma unroll
  for (int j = 0; j < DCONV; j++) {
    int lj = l - (DCONV - 1) + j;
    if (lj >= 0) s += xz[(row - (DCONV - 1) + j) * (2 * DI) + d] * w[j];
  }
  uc[i] = s * sigmoidf_(s);
}

// ============ chunked selective scan ============
// state index mapping: gi = ((b*NCH + c)*DI + d)*DS + s   (pass 1/3)
//                      gj = (b*DI + d)*DS + s             (pass 2)

// ---- pass 1: per-chunk local scan from h=0; emit (exp(a*sum_dt), h_local) ----
__global__ __launch_bounds__(256) void k_scan1(const float* __restrict__ dt,
                                               const float* __restrict__ uc,
                                               const float* __restrict__ xdbl,
                                               const float* __restrict__ A_log,
                                               float* __restrict__ cA,
                                               float* __restrict__ cB) {
  int gi = blockIdx.x * 256 + threadIdx.x;
  int s = gi & 15;
  int rest = gi >> 4;          // [b][c][d]
  int d = rest % DI;
  int rest2 = rest / DI;
  int c = rest2 % NCH;
  int b = rest2 / NCH;
  float a = -__expf(A_log[d * DS + s]);
  long l0 = (long)c * CT;
  const float* dtp = dt + ((long)b * SEQL + l0) * DI + d;
  const float* ucp = uc + ((long)b * SEQL + l0) * DI + d;
  const float* Bp  = xdbl + ((long)b * SEQL + l0) * 80 + DTR + s;
  float S = 0.f, hh = 0.f;
#pragma unroll 4
  for (int l = 0; l < CT; l++) {
    float dtv = dtp[(long)l * DI];
    float uv  = ucp[(long)l * DI];
    float Bv  = Bp[(long)l * 80];
    S += dtv;
    hh = __expf(dtv * a) * hh + (dtv * uv) * Bv;
  }
  cA[gi] = __expf(a * S);
  cB[gi] = hh;
}

// ---- pass 2: sequential combine of chunk aggregates -> chunk start states ----
__global__ __launch_bounds__(256) void k_scan2(const float* __restrict__ cA,
                                               const float* __restrict__ cB,
                                               float* __restrict__ hst) {
  int gj = blockIdx.x * 256 + threadIdx.x;   // [b][d][s]
  int ds_ = gj & (DI * DS - 1);              // DI*DS = 24576, pow2
  int b = gj / (DI * DS);
  float h = 0.f;
#pragma unroll
  for (int c = 0; c < NCH; c++) {
    long idx = ((long)(b * NCH + c) * DI * DS) + ds_;
    hst[idx] = h;
    h = cA[idx] * h + cB[idx];
  }
}

// ---- pass 3: rerun local scan from true start state, emit y ----
__global__ __launch_bounds__(256) void k_scan3(const float* __restrict__ dt,
                                               const float* __restrict__ uc,
                                               const float* __restrict__ xdbl,
                                               const float* __restrict__ A_log,
                                               const float* __restrict__ hst,
                                               float* __restrict__ ys) {
  int gi = blockIdx.x * 256 + threadIdx.x;
  int s = gi & 15;
  int rest = gi >> 4;
  int d = rest % DI;
  int rest2 = rest / DI;
  int c = rest2 % NCH;
  int b = rest2 / NCH;
  float a = -__expf(A_log[d * DS + s]);
  long l0 = (long)c * CT;
  const float* dtp = dt + ((long)b * SEQL + l0) * DI + d;
  const float* ucp = uc + ((long)b * SEQL + l0) * DI + d;
  const float* Bp  = xdbl + ((long)b * SEQL + l0) * 80 + DTR + s;
  const float* Cp  = Bp + DS;
  float* yp = ys + ((long)b * SEQL + l0) * DI + d;
  float h = hst[gi];
#pragma unroll 4
  for (int l = 0; l < CT; l++) {
    float dtv = dtp[(long)l * DI];
    float uv  = ucp[(long)l * DI];
    float Bv  = Bp[(long)l * 80];
    float Cv  = Cp[(long)l * 80];
    h = __expf(dtv * a) * h + (dtv * uv) * Bv;
    float y = h * Cv;
    y += __shfl_xor(y, 1);
    y += __shfl_xor(y, 2);
    y += __shfl_xor(y, 4);
    y += __shfl_xor(y, 8);
    if (s == 0) yp[(long)l * DI] = y;
  }
}

// ---------------- skip + gate, write bf16 A-operand ----------------
__global__ __launch_bounds__(256) void k_gate(const float* __restrict__ ys,
                                              const float* __restrict__ uc,
                                              const float* __restrict__ xz,
                                              const float* __restrict__ Dsk,
                                              bf16_t* __restrict__ o, long total) {
  long i = (long)blockIdx.x * 256 + threadIdx.x;
  if (i >= total) return;
  int d = (int)(i % DI);
  long row = i / DI;
  float y = ys[i] + uc[i] * Dsk[d];
  float z = xz[row * (2 * DI) + DI + d];
  o[i] = (bf16_t)(y * z * sigmoidf_(z));
}

// ---------------- final LayerNorm, write bf16 A-operand ----------------
__global__ __launch_bounds__(256) void k_ln(const float* __restrict__ h,
                                            const float* __restrict__ g,
                                            const float* __restrict__ bta,
                                            bf16_t* __restrict__ o) {
  __shared__ float sm[4];
  int row = blockIdx.x;
  int t = threadIdx.x;
  const float* hr = h + (long)row * DM;
  float v0 = hr[t], v1 = hr[t + 256], v2 = hr[t + 512];
  float s = v0 + v1 + v2;
#pragma unroll
  for (int off = 32; off > 0; off >>= 1) s += __shfl_down(s, off);
  if ((t & 63) == 0) sm[t >> 6] = s;
  __syncthreads();
  float mu = (sm[0] + sm[1] + sm[2] + sm[3]) * (1.f / DM);
  __syncthreads();
  float d0 = v0 - mu, d1 = v1 - mu, d2 = v2 - mu;
  float q = d0 * d0 + d1 * d1 + d2 * d2;
#pragma unroll
  for (int off = 32; off > 0; off >>= 1) q += __shfl_down(q, off);
  if ((t & 63) == 0) sm[t >> 6] = q;
  __syncthreads();
  float var = (sm[0] + sm[1] + sm[2] + sm[3]) * (1.f / DM);
  float rs = rsqrtf(var + 1e-5f);
  bf16_t* orow = o + (long)row * DM;
  orow[t]       = (bf16_t)(d0 * rs * g[t]       + bta[t]);
  orow[t + 256] = (bf16_t)(d1 * rs * g[t + 256] + bta[t + 256]);
  orow[t + 512] = (bf16_t)(d2 * rs * g[t + 512] + bta[t + 512]);
}

// ---------------- bf16 MFMA GEMM, NT: C(MxN) = A(MxK) * W(NxK)^T ----------------
// EPI: 0 = plain, 1 = +bias[n], 2 = += C (residual), 3 = softplus(acc + bias[n])
__device__ __forceinline__ void stage16(const bf16_t* gp, bf16_t* lp) {
  __builtin_amdgcn_global_load_lds(
      (const __attribute__((address_space(1))) uint32_t*)gp,
      (__attribute__((address_space(3))) uint32_t*)lp, 16, 0, 0);
}

template <int EPI>
__global__ __launch_bounds__(256) void k_gemm(const bf16_t* __restrict__ A,
                                              const bf16_t* __restrict__ W,
                                              float* __restrict__ C,
                                              const float* __restrict__ bias,
                                              int M, int N, int K, int ldc) {
  __shared__ bf16_t lA[128 * 32];
  __shared__ bf16_t lB[128 * 32];
  const int tid = threadIdx.x;
  const int lane = tid & 63;
  const int wv = tid >> 6;
  const int wm = wv >> 1, wn = wv & 1;
  const long m0 = (long)blockIdx.y * 128;
  const long n0 = (long)blockIdx.x * 128;
  const int r0 = tid >> 2;             // staging row 0..63
  const int c8 = (tid & 3) * 8;        // staging col (elems)
  const int fr = lane & 15;            // fragment row
  const int kq = lane >> 4;            // k-quarter

  f32x4 acc[4][4];
#pragma unroll
  for (int i = 0; i < 4; i++)
#pragma unroll
    for (int j = 0; j < 4; j++) acc[i][j] = (f32x4){0.f, 0.f, 0.f, 0.f};

  const bf16_t* Ab = A + (m0 + r0) * (long)K + c8;
  const bf16_t* Wb = W + (n0 + r0) * (long)K + c8;
  bf16_t* lAp = lA + r0 * 32 + c8;
  bf16_t* lBp = lB + r0 * 32 + c8;
  const long s64K = 64L * K;

  for (int k0 = 0; k0 < K; k0 += 32) {
    __syncthreads();
    stage16(Ab + k0, lAp);
    stage16(Ab + k0 + s64K, lAp + 64 * 32);
    stage16(Wb + k0, lBp);
    stage16(Wb + k0 + s64K, lBp + 64 * 32);
    __syncthreads();  // compiler emits vmcnt(0) drain before barrier
    bf16x8 af[4], bfv[4];
#pragma unroll
    for (int f = 0; f < 4; f++)
      af[f] = *(const bf16x8*)&lA[(wm * 64 + f * 16 + fr) * 32 + kq * 8];
#pragma unroll
    for (int f = 0; f < 4; f++)
      bfv[f] = *(const bf16x8*)&lB[(wn * 64 + f * 16 + fr) * 32 + kq * 8];
#pragma unroll
    for (int fm = 0; fm < 4; fm++)
#pragma unroll
      for (int fn = 0; fn < 4; fn++)
        acc[fm][fn] = __builtin_amdgcn_mfma_f32_16x16x32_bf16(af[fm], bfv[fn],
                                                              acc[fm][fn], 0, 0, 0);
  }

  const int r4 = (lane >> 4) * 4;
  const int cc = lane & 15;
#pragma unroll
  for (int fm = 0; fm < 4; fm++) {
    long rowb = m0 + wm * 64 + fm * 16 + r4;
#pragma unroll
    for (int fn = 0; fn < 4; fn++) {
      long col = n0 + wn * 64 + fn * 16 + cc;
      if (col < N) {
        float bv = (EPI == 1 || EPI == 3) ? bias[col] : 0.f;
#pragma unroll
        for (int r = 0; r < 4; r++) {
          long row = rowb + r;
          float v = acc[fm][fn][r];
          if (EPI == 1) v += bv;
          else if (EPI == 3) { v += bv; v = (v > 20.f) ? v : log1pf(__expf(v)); }
          else if (EPI == 2) v += C[row * (long)ldc + col];
          C[row * (long)ldc + col] = v;
        }
      }
    }
  }
}

static inline int cdiv_l(long a, long b) { return (int)((a + b - 1) / b); }

extern "C" void kernel_launch(void* const* d_in, const int* in_sizes, int n_in,
                              void* d_out, int out_size, void* d_ws, size_t ws_size,
                              hipStream_t stream) {
  (void)in_sizes; (void)n_in; (void)out_size; (void)ws_size;
  const int*   x      = (const int*)  d_in[0];
  const float* emb    = (const float*)d_in[1];
  const float* W_in   = (const float*)d_in[2];
  const float* conv_w = (const float*)d_in[3];
  const float* conv_b = (const float*)d_in[4];
  const float* W_x    = (const float*)d_in[5];
  const float* W_dt   = (const float*)d_in[6];
  const float* b_dt   = (const float*)d_in[7];
  const float* A_log  = (const float*)d_in[8];
  const float* D_skip = (const float*)d_in[9];
  const float* W_out  = (const float*)d_in[10];
  const float* ln_g   = (const float*)d_in[11];
  const float* ln_b   = (const float*)d_in[12];
  const float* head_w = (const float*)d_in[13];
  const float* head_b = (const float*)d_in[14];
  float* out = (float*)d_out;

  // bf16 staging in d_ws (must be live during head GEMM): 61.8 MB
  char* ws = (char*)d_ws;
  bf16_t* abuf = (bf16_t*)ws;                               // up to BL*DI bf16
  bf16_t* wbuf = (bf16_t*)(ws + (size_t)BL * DI * 2);       // up to VOC*DM bf16

  // f32 intermediates overlaid into d_out (131M floats; all dead before head GEMM)
  float* xz   = out;                         // BL * 2*DI
  float* uc   = xz   + (size_t)BL * 2 * DI;  // BL * DI
  float* xdbl = uc   + (size_t)BL * DI;      // BL * 80
  float* dtb  = xdbl + (size_t)BL * 80;      // BL * DI
  float* ysb  = dtb  + (size_t)BL * DI;      // BL * DI
  float* h    = ysb  + (size_t)BL * DI;      // BL * DM
  float* cA   = h    + (size_t)BL * DM;      // BATCH*NCH*DI*DS
  float* cB   = cA   + (size_t)BATCH * NCH * DI * DS;
  float* hst  = cB   + (size_t)BATCH * NCH * DI * DS;   // ends ~39.6M floats

  const int scan_blocks = BATCH * NCH * DI * DS / 256;  // 6144
  const int st_blocks   = BATCH * DI * DS / 256;        // 192

  k_embed<<<BL, 256, 0, stream>>>(x, emb, h);

  for (int l = 0; l < NL; ++l) {
    // ---- in_proj: xz = h @ W_in^T  (4096 x 3072, K=768) ----
    k_cvt<<<cdiv_l((long)BL * DM / 4, 256), 256, 0, stream>>>(h, abuf, (long)BL * DM / 4);
    k_cvt<<<cdiv_l((long)2 * DI * DM / 4, 256), 256, 0, stream>>>(
        W_in + (size_t)l * 2 * DI * DM, wbuf, (long)2 * DI * DM / 4);
    k_gemm<0><<<dim3(2 * DI / 128, BL / 128), 256, 0, stream>>>(
        abuf, wbuf, xz, nullptr, BL, 2 * DI, DM, 2 * DI);
    // ---- causal dw-conv + silu ----
    k_conv<<<cdiv_l((long)BL * DI, 256), 256, 0, stream>>>(
        xz, conv_w + (size_t)l * DI * DCONV, conv_b + (size_t)l * DI, uc, (long)BL * DI);
    // ---- x_proj: xdbl = uc @ W_x^T  (4096 x 80, K=1536; W padded to 128 rows) ----
    k_cvt<<<cdiv_l((long)BL * DI / 4, 256), 256, 0, stream>>>(uc, abuf, (long)BL * DI / 4);
    k_cvt_pad<<<cdiv_l(128L * DI, 256), 256, 0, stream>>>(
        W_x + (size_t)l * 80 * DI, wbuf, 80, DI, DI, DI, 128L * DI);
    k_gemm<0><<<dim3(1, BL / 128), 256, 0, stream>>>(
        abuf, wbuf, xdbl, nullptr, BL, 80, DI, 80);
    // ---- dt = softplus(dtlin @ W_dt^T + b_dt)  (K=48 padded to 64) ----
    k_cvt_pad<<<cdiv_l((long)BL * 64, 256), 256, 0, stream>>>(
        xdbl, abuf, BL, DTR, 80, 64, (long)BL * 64);
    k_cvt_pad<<<cdiv_l((long)DI * 64, 256), 256, 0, stream>>>(
        W_dt + (size_t)l * DI * DTR, wbuf, DI, DTR, DTR, 64, (long)DI * 64);
    k_gemm<3><<<dim3(DI / 128, BL / 128), 256, 0, stream>>>(
        abuf, wbuf, dtb, b_dt + (size_t)l * DI, BL, DI, 64, DI);
    // ---- chunked selective scan ----
    k_scan1<<<scan_blocks, 256, 0, stream>>>(dtb, uc, xdbl,
                                             A_log + (size_t)l * DI * DS, cA, cB);
    k_scan2<<<st_blocks, 256, 0, stream>>>(cA, cB, hst);
    k_scan3<<<scan_blocks, 256, 0, stream>>>(dtb, uc, xdbl,
                                             A_log + (size_t)l * DI * DS, hst, ysb);
    // ---- skip + gate -> bf16 ----
    k_gate<<<cdiv_l((long)BL * DI, 256), 256, 0, stream>>>(
        ysb, uc, xz, D_skip + (size_t)l * DI, abuf, (long)BL * DI);
    // ---- out_proj + residual: h += y @ W_out^T  (4096 x 768, K=1536) ----
    k_cvt<<<cdiv_l((long)DM * DI / 4, 256), 256, 0, stream>>>(
        W_out + (size_t)l * DM * DI, wbuf, (long)DM * DI / 4);
    k_gemm<2><<<dim3(DM / 128, BL / 128), 256, 0, stream>>>(
        abuf, wbuf, h, nullptr, BL, DM, DI, DM);
  }

  // ---- final LN -> bf16, head GEMM + bias ----
  k_ln<<<BL, 256, 0, stream>>>(h, ln_g, ln_b, abuf);
  k_cvt<<<cdiv_l((long)VOC * DM / 4, 256), 256, 0, stream>>>(head_w, wbuf, (long)VOC * DM / 4);
  k_gemm<1><<<dim3(VOC / 128, BL / 128), 256, 0, stream>>>(
      abuf, wbuf, out, head_b, BL, VOC, DM, VOC);
}

// Round 3
// 1016.400 us; speedup vs baseline: 2.5752x; 1.1047x over previous
//
#include <hip/hip_runtime.h>
#include <hip/hip_bf16.h>
#include <stdint.h>

#define BL    4096      // BATCH*SEQ
#define DM    768       // d_model
#define DI    1536      // d_inner
#define DS    16        // d_state
#define DCONV 4
#define DTR   48        // dt_rank
#define NL    2
#define SEQL  2048
#define BATCH 2
#define VOC   32000
#define NCH   32        // scan chunks
#define CT    64        // steps per chunk (SEQL/NCH)

typedef __bf16 bf16_t;
typedef __bf16 bf16x8 __attribute__((ext_vector_type(8)));
typedef __bf16 bf16x4 __attribute__((ext_vector_type(4)));
typedef float  f32x4  __attribute__((ext_vector_type(4)));

__device__ __forceinline__ float sigmoidf_(float x) { return 1.f / (1.f + __expf(-x)); }

// ---------------- embedding gather ----------------
__global__ __launch_bounds__(256) void k_embed(const int* __restrict__ x,
                                               const float* __restrict__ emb,
                                               float* __restrict__ h) {
  int row = blockIdx.x;
  int tok = x[row];
  const float* e = emb + (size_t)tok * DM;
  float* hr = h + (size_t)row * DM;
  for (int c = threadIdx.x; c < DM; c += 256) hr[c] = e[c];
}

// ---------------- f32 -> bf16, vectorized (n % 4 == 0) ----------------
__global__ __launch_bounds__(256) void k_cvt(const float* __restrict__ src,
                                             bf16_t* __restrict__ dst, long n4) {
  long i = (long)blockIdx.x * 256 + threadIdx.x;
  if (i >= n4) return;
  float4 v = ((const float4*)src)[i];
  bf16x4 o;
  o[0] = (bf16_t)v.x; o[1] = (bf16_t)v.y; o[2] = (bf16_t)v.z; o[3] = (bf16_t)v.w;
  ((bf16x4*)dst)[i] = o;
}

// ---------------- f32 -> bf16 with zero padding (R x C, ld srcLd -> Rpad x Cpad) ----
__global__ __launch_bounds__(256) void k_cvt_pad(const float* __restrict__ src,
                                                 bf16_t* __restrict__ dst,
                                                 int R, int C, int srcLd, int Cpad,
                                                 long total) {
  long i = (long)blockIdx.x * 256 + threadIdx.x;
  if (i >= total) return;
  int r = (int)(i / Cpad), c = (int)(i % Cpad);
  float v = (r < R && c < C) ? src[(size_t)r * srcLd + c] : 0.f;
  dst[i] = (bf16_t)v;
}

// ---------------- causal depthwise conv (w=4) + bias + silu ----------------
__global__ __launch_bounds__(256) void k_conv(const float* __restrict__ xz,
                                              const float* __restrict__ cw,
                                              const float* __restrict__ cb,
                                              float* __restrict__ uc, long total) {
  long i = (long)blockIdx.x * 256 + threadIdx.x;
  if (i >= total) return;
  int d = (int)(i % DI);
  long row = i / DI;
  int l = (int)(row % SEQL);
  const float* w = cw + (size_t)d * DCONV;
  float s = cb[d];
#pragma unroll
  for (int j = 0; j < DCONV; j++) {
    int lj = l - (DCONV - 1) + j;
    if (lj >= 0) s += xz[(row - (DCONV - 1) + j) * (2 * DI) + d] * w[j];
  }
  uc[i] = s * sigmoidf_(s);
}

// ============ chunked selective scan ============
__global__ __launch_bounds__(256) void k_scan1(const float* __restrict__ dt,
                                               const float* __restrict__ uc,
                                               const float* __restrict__ xdbl,
                                               const float* __restrict__ A_log,
                                               float* __restrict__ cA,
                                               float* __restrict__ cB) {
  int gi = blockIdx.x * 256 + threadIdx.x;
  int s = gi & 15;
  int rest = gi >> 4;          // [b][c][d]
  int d = rest % DI;
  int rest2 = rest / DI;
  int c = rest2 % NCH;
  int b = rest2 / NCH;
  float a = -__expf(A_log[d * DS + s]);
  long l0 = (long)c * CT;
  const float* dtp = dt + ((long)b * SEQL + l0) * DI + d;
  const float* ucp = uc + ((long)b * SEQL + l0) * DI + d;
  const float* Bp  = xdbl + ((long)b * SEQL + l0) * 80 + DTR + s;
  float S = 0.f, hh = 0.f;
#pragma unroll 4
  for (int l = 0; l < CT; l++) {
    float dtv = dtp[(long)l * DI];
    float uv  = ucp[(long)l * DI];
    float Bv  = Bp[(long)l * 80];
    S += dtv;
    hh = __expf(dtv * a) * hh + (dtv * uv) * Bv;
  }
  cA[gi] = __expf(a * S);
  cB[gi] = hh;
}

__global__ __launch_bounds__(256) void k_scan2(const float* __restrict__ cA,
                                               const float* __restrict__ cB,
                                               float* __restrict__ hst) {
  int gj = blockIdx.x * 256 + threadIdx.x;   // [b][d][s]
  int ds_ = gj & (DI * DS - 1);
  int b = gj / (DI * DS);
  float h = 0.f;
#pragma unroll
  for (int c = 0; c < NCH; c++) {
    long idx = ((long)(b * NCH + c) * DI * DS) + ds_;
    hst[idx] = h;
    h = cA[idx] * h + cB[idx];
  }
}

__global__ __launch_bounds__(256) void k_scan3(const float* __restrict__ dt,
                                               const float* __restrict__ uc,
                                               const float* __restrict__ xdbl,
                                               const float* __restrict__ A_log,
                                               const float* __restrict__ hst,
                                               float* __restrict__ ys) {
  int gi = blockIdx.x * 256 + threadIdx.x;
  int s = gi & 15;
  int rest = gi >> 4;
  int d = rest % DI;
  int rest2 = rest / DI;
  int c = rest2 % NCH;
  int b = rest2 / NCH;
  float a = -__expf(A_log[d * DS + s]);
  long l0 = (long)c * CT;
  const float* dtp = dt + ((long)b * SEQL + l0) * DI + d;
  const float* ucp = uc + ((long)b * SEQL + l0) * DI + d;
  const float* Bp  = xdbl + ((long)b * SEQL + l0) * 80 + DTR + s;
  const float* Cp  = Bp + DS;
  float* yp = ys + ((long)b * SEQL + l0) * DI + d;
  float h = hst[gi];
#pragma unroll 4
  for (int l = 0; l < CT; l++) {
    float dtv = dtp[(long)l * DI];
    float uv  = ucp[(long)l * DI];
    float Bv  = Bp[(long)l * 80];
    float Cv  = Cp[(long)l * 80];
    h = __expf(dtv * a) * h + (dtv * uv) * Bv;
    float y = h * Cv;
    y += __shfl_xor(y, 1);
    y += __shfl_xor(y, 2);
    y += __shfl_xor(y, 4);
    y += __shfl_xor(y, 8);
    if (s == 0) yp[(long)l * DI] = y;
  }
}

// ---------------- skip + gate, write bf16 A-operand ----------------
__global__ __launch_bounds__(256) void k_gate(const float* __restrict__ ys,
                                              const float* __restrict__ uc,
                                              const float* __restrict__ xz,
                                              const float* __restrict__ Dsk,
                                              bf16_t* __restrict__ o, long total) {
  long i = (long)blockIdx.x * 256 + threadIdx.x;
  if (i >= total) return;
  int d = (int)(i % DI);
  long row = i / DI;
  float y = ys[i] + uc[i] * Dsk[d];
  float z = xz[row * (2 * DI) + DI + d];
  o[i] = (bf16_t)(y * z * sigmoidf_(z));
}

// ---------------- final LayerNorm, write bf16 A-operand ----------------
__global__ __launch_bounds__(256) void k_ln(const float* __restrict__ h,
                                            const float* __restrict__ g,
                                            const float* __restrict__ bta,
                                            bf16_t* __restrict__ o) {
  __shared__ float sm[4];
  int row = blockIdx.x;
  int t = threadIdx.x;
  const float* hr = h + (long)row * DM;
  float v0 = hr[t], v1 = hr[t + 256], v2 = hr[t + 512];
  float s = v0 + v1 + v2;
#pragma unroll
  for (int off = 32; off > 0; off >>= 1) s += __shfl_down(s, off);
  if ((t & 63) == 0) sm[t >> 6] = s;
  __syncthreads();
  float mu = (sm[0] + sm[1] + sm[2] + sm[3]) * (1.f / DM);
  __syncthreads();
  float d0 = v0 - mu, d1 = v1 - mu, d2 = v2 - mu;
  float q = d0 * d0 + d1 * d1 + d2 * d2;
#pragma unroll
  for (int off = 32; off > 0; off >>= 1) q += __shfl_down(q, off);
  if ((t & 63) == 0) sm[t >> 6] = q;
  __syncthreads();
  float var = (sm[0] + sm[1] + sm[2] + sm[3]) * (1.f / DM);
  float rs = rsqrtf(var + 1e-5f);
  bf16_t* orow = o + (long)row * DM;
  orow[t]       = (bf16_t)(d0 * rs * g[t]       + bta[t]);
  orow[t + 256] = (bf16_t)(d1 * rs * g[t + 256] + bta[t + 256]);
  orow[t + 512] = (bf16_t)(d2 * rs * g[t + 512] + bta[t + 512]);
}

// ---------------- 128^2 bf16 MFMA GEMM (skinny shapes), NT layout ----------------
// EPI: 0 = plain, 1 = +bias[n], 2 = += C (residual), 3 = softplus(acc + bias[n])
__device__ __forceinline__ void stage16(const bf16_t* gp, bf16_t* lp) {
  __builtin_amdgcn_global_load_lds(
      (const __attribute__((address_space(1))) uint32_t*)gp,
      (__attribute__((address_space(3))) uint32_t*)lp, 16, 0, 0);
}

template <int EPI>
__global__ __launch_bounds__(256) void k_gemm(const bf16_t* __restrict__ A,
                                              const bf16_t* __restrict__ W,
                                              float* __restrict__ C,
                                              const float* __restrict__ bias,
                                              int M, int N, int K, int ldc) {
  __shared__ bf16_t lA[128 * 32];
  __shared__ bf16_t lB[128 * 32];
  const int tid = threadIdx.x;
  const int lane = tid & 63;
  const int wv = tid >> 6;
  const int wm = wv >> 1, wn = wv & 1;
  const long m0 = (long)blockIdx.y * 128;
  const long n0 = (long)blockIdx.x * 128;
  const int r0 = tid >> 2;
  const int c8 = (tid & 3) * 8;
  const int fr = lane & 15;
  const int kq = lane >> 4;

  f32x4 acc[4][4];
#pragma unroll
  for (int i = 0; i < 4; i++)
#pragma unroll
    for (int j = 0; j < 4; j++) acc[i][j] = (f32x4){0.f, 0.f, 0.f, 0.f};

  const bf16_t* Ab = A + (m0 + r0) * (long)K + c8;
  const bf16_t* Wb = W + (n0 + r0) * (long)K + c8;
  bf16_t* lAp = lA + r0 * 32 + c8;
  bf16_t* lBp = lB + r0 * 32 + c8;
  const long s64K = 64L * K;

  for (int k0 = 0; k0 < K; k0 += 32) {
    __syncthreads();
    stage16(Ab + k0, lAp);
    stage16(Ab + k0 + s64K, lAp + 64 * 32);
    stage16(Wb + k0, lBp);
    stage16(Wb + k0 + s64K, lBp + 64 * 32);
    __syncthreads();
    bf16x8 af[4], bfv[4];
#pragma unroll
    for (int f = 0; f < 4; f++)
      af[f] = *(const bf16x8*)&lA[(wm * 64 + f * 16 + fr) * 32 + kq * 8];
#pragma unroll
    for (int f = 0; f < 4; f++)
      bfv[f] = *(const bf16x8*)&lB[(wn * 64 + f * 16 + fr) * 32 + kq * 8];
#pragma unroll
    for (int fm = 0; fm < 4; fm++)
#pragma unroll
      for (int fn = 0; fn < 4; fn++)
        acc[fm][fn] = __builtin_amdgcn_mfma_f32_16x16x32_bf16(af[fm], bfv[fn],
                                                              acc[fm][fn], 0, 0, 0);
  }

  const int r4 = (lane >> 4) * 4;
  const int cc = lane & 15;
#pragma unroll
  for (int fm = 0; fm < 4; fm++) {
    long rowb = m0 + wm * 64 + fm * 16 + r4;
#pragma unroll
    for (int fn = 0; fn < 4; fn++) {
      long col = n0 + wn * 64 + fn * 16 + cc;
      if (col < N) {
        float bv = (EPI == 1 || EPI == 3) ? bias[col] : 0.f;
#pragma unroll
        for (int r = 0; r < 4; r++) {
          long row = rowb + r;
          float v = acc[fm][fn][r];
          if (EPI == 1) v += bv;
          else if (EPI == 3) { v += bv; v = (v > 20.f) ? v : log1pf(__expf(v)); }
          else if (EPI == 2) v += C[row * (long)ldc + col];
          C[row * (long)ldc + col] = v;
        }
      }
    }
  }
}

// ---------------- 256^2 8-phase counted-vmcnt bf16 GEMM (big shapes) ----------------
// C(MxN) = A(MxK) * W(NxK)^T. Requires M%256==0, N%256==0, K%64==0, K/64>=2,
// grid%8==0. Per K-tile issue order [A0,A2,B0,B1,B2,B3,A1,A3]: phase(mg=0)
// consumes the first 6 (A0/A2 + all B), phase(mg=1) the last 2 -> vmcnt(2)
// suffices at both per-tile barriers (counted, never 0 except final tile).
// LDS XOR-swizzle byte^=(row&7)<<4 applied on read; staging pre-swizzles the
// GLOBAL source column (rule #21) since global_load_lds writes linearly.

#define GLD256(ab, j, ktt, pp) do {                                             \
    int idx_ = (j) * 512 + tid;                                                 \
    int r_ = idx_ >> 3; int c16_ = idx_ & 7;                                    \
    size_t col_ = (size_t)(ktt) * 64 + (size_t)((c16_ ^ (r_ & 7)) << 3);        \
    const bf16_t* gp_ = (ab) ? (Wp + ((size_t)(n0 + r_)) * K + col_)            \
                             : (Ap + ((size_t)(m0 + r_)) * K + col_);           \
    bf16_t* lp_ = lds + ((((pp) * 2 + (ab)) * 256 + r_) * 64) + c16_ * 8;       \
    __builtin_amdgcn_global_load_lds(                                           \
        (const __attribute__((address_space(1))) uint32_t*)gp_,                 \
        (__attribute__((address_space(3))) uint32_t*)lp_, 16, 0, 0);            \
  } while (0)

#define STAGE2(pp, ktt, s) do {                                                 \
    if ((s) == 0) { GLD256(0, 0, ktt, pp); GLD256(0, 2, ktt, pp); }             \
    if ((s) == 1) { GLD256(1, 0, ktt, pp); GLD256(1, 1, ktt, pp); }             \
    if ((s) == 2) { GLD256(1, 2, ktt, pp); GLD256(1, 3, ktt, pp); }             \
    if ((s) == 3) { GLD256(0, 1, ktt, pp); GLD256(0, 3, ktt, pp); }             \
  } while (0)

#define COMPUTE256(pp, mg, kh) do {                                             \
    const char* lb_ = (const char*)lds;                                         \
    bf16x8 af_[4], bv_[4];                                                      \
    _Pragma("unroll") for (int f = 0; f < 4; ++f) {                             \
      int row_ = wm * 128 + (mg) * 64 + f * 16 + fr;                            \
      int byte_ = (((pp) * 2 + 0) * 256 + row_) * 128 +                         \
                  (((kh) * 64 + kq * 16) ^ ((row_ & 7) << 4));                  \
      af_[f] = *(const bf16x8*)(lb_ + byte_);                                   \
    }                                                                           \
    _Pragma("unroll") for (int f = 0; f < 4; ++f) {                             \
      int row_ = wn * 64 + f * 16 + fr;                                         \
      int byte_ = (((pp) * 2 + 1) * 256 + row_) * 128 +                         \
                  (((kh) * 64 + kq * 16) ^ ((row_ & 7) << 4));                  \
      bv_[f] = *(const bf16x8*)(lb_ + byte_);                                   \
    }                                                                           \
    __builtin_amdgcn_s_setprio(1);                                              \
    _Pragma("unroll") for (int fm = 0; fm < 4; ++fm)                            \
      _Pragma("unroll") for (int fn = 0; fn < 4; ++fn)                          \
        acc[(mg) * 4 + fm][fn] = __builtin_amdgcn_mfma_f32_16x16x32_bf16(       \
            af_[fm], bv_[fn], acc[(mg) * 4 + fm][fn], 0, 0, 0);                 \
    __builtin_amdgcn_s_setprio(0);                                              \
  } while (0)

#define WAITV2()  asm volatile("s_waitcnt vmcnt(2)" ::: "memory")
#define WAITV0()  asm volatile("s_waitcnt vmcnt(0)" ::: "memory")
#define BARRIER() do { __builtin_amdgcn_s_barrier();                            \
                       asm volatile("" ::: "memory"); } while (0)

template <int EPI>
__global__ __launch_bounds__(512, 2) void k_gemm256(const bf16_t* __restrict__ Ap,
                                                    const bf16_t* __restrict__ Wp,
                                                    float* __restrict__ C,
                                                    const float* __restrict__ bias,
                                                    int K, int ldc, int nxtile) {
  __shared__ bf16_t lds[2 * 2 * 256 * 64];   // 128 KiB: [buf][A|B][256][64]
  const int tid = threadIdx.x;
  const int lane = tid & 63;
  const int wid = tid >> 6;
  const int wm = wid >> 2, wn = wid & 3;
  const int fr = lane & 15, kq = lane >> 4;

  // bijective XCD swizzle (grid % 8 == 0)
  const int cpx = gridDim.x >> 3;
  const int wg = ((int)blockIdx.x & 7) * cpx + ((int)blockIdx.x >> 3);
  const long m0 = (long)(wg / nxtile) * 256;
  const long n0 = (long)(wg % nxtile) * 256;

  f32x4 acc[8][4];
#pragma unroll
  for (int i = 0; i < 8; i++)
#pragma unroll
    for (int j = 0; j < 4; j++) acc[i][j] = (f32x4){0.f, 0.f, 0.f, 0.f};

  // prologue: stage tile 0; establish invariant (first 6 done, last 2 may fly)
  STAGE2(0, 0, 0); STAGE2(0, 0, 1); STAGE2(0, 0, 2); STAGE2(0, 0, 3);
  WAITV2();
  BARRIER();

  const int NT = K >> 6;
  for (int kt = 0; kt < NT; ++kt) {
    const int p = kt & 1;
    const bool pre = (kt + 1 < NT);
    // phase 0 (mg=0, kh=0)
    if (pre) STAGE2(p ^ 1, kt + 1, 0);
    COMPUTE256(p, 0, 0);
    // phase 1 boundary: current tile's A1/A3 must land
    if (pre) WAITV2(); else WAITV0();
    BARRIER();
    if (pre) STAGE2(p ^ 1, kt + 1, 1);
    COMPUTE256(p, 1, 0);
    // phase 2 (data already visible)
    if (pre) STAGE2(p ^ 1, kt + 1, 2);
    COMPUTE256(p, 0, 1);
    // phase 3
    if (pre) STAGE2(p ^ 1, kt + 1, 3);
    COMPUTE256(p, 1, 1);
    // tile switch: next tile's first 6 must land
    if (pre) {
      WAITV2();
      BARRIER();
    }
  }

  const int r4 = (lane >> 4) * 4;
  const int cc = lane & 15;
#pragma unroll
  for (int m = 0; m < 8; m++) {
    long rowb = m0 + wm * 128 + (m >> 2) * 64 + (m & 3) * 16 + r4;
#pragma unroll
    for (int n = 0; n < 4; n++) {
      long col = n0 + wn * 64 + n * 16 + cc;
      float bv = (EPI == 1) ? bias[col] : 0.f;
#pragma unroll
      for (int r = 0; r < 4; r++) {
        float v = acc[m][n][r];
        if (EPI == 1) v += bv;
        C[(rowb + r) * (long)ldc + col] = v;
      }
    }
  }
}

static inline int cdiv_l(long a, long b) { return (int)((a + b - 1) / b); }

extern "C" void kernel_launch(void* const* d_in, const int* in_sizes, int n_in,
                              void* d_out, int out_size, void* d_ws, size_t ws_size,
                              hipStream_t stream) {
  (void)in_sizes; (void)n_in; (void)out_size; (void)ws_size;
  const int*   x      = (const int*)  d_in[0];
  const float* emb    = (const float*)d_in[1];
  const float* W_in   = (const float*)d_in[2];
  const float* conv_w = (const float*)d_in[3];
  const float* conv_b = (const float*)d_in[4];
  const float* W_x    = (const float*)d_in[5];
  const float* W_dt   = (const float*)d_in[6];
  const float* b_dt   = (const float*)d_in[7];
  const float* A_log  = (const float*)d_in[8];
  const float* D_skip = (const float*)d_in[9];
  const float* W_out  = (const float*)d_in[10];
  const float* ln_g   = (const float*)d_in[11];
  const float* ln_b   = (const float*)d_in[12];
  const float* head_w = (const float*)d_in[13];
  const float* head_b = (const float*)d_in[14];
  float* out = (float*)d_out;

  // bf16 staging in d_ws (live during head GEMM): 61.8 MB
  char* ws = (char*)d_ws;
  bf16_t* abuf = (bf16_t*)ws;                               // up to BL*DI bf16
  bf16_t* wbuf = (bf16_t*)(ws + (size_t)BL * DI * 2);       // up to VOC*DM bf16

  // f32 intermediates overlaid into d_out (131M floats; all dead before head GEMM)
  float* xz   = out;
  float* uc   = xz   + (size_t)BL * 2 * DI;
  float* xdbl = uc   + (size_t)BL * DI;
  float* dtb  = xdbl + (size_t)BL * 80;
  float* ysb  = dtb  + (size_t)BL * DI;
  float* h    = ysb  + (size_t)BL * DI;
  float* cA   = h    + (size_t)BL * DM;
  float* cB   = cA   + (size_t)BATCH * NCH * DI * DS;
  float* hst  = cB   + (size_t)BATCH * NCH * DI * DS;

  const int scan_blocks = BATCH * NCH * DI * DS / 256;  // 6144
  const int st_blocks   = BATCH * DI * DS / 256;        // 192

  k_embed<<<BL, 256, 0, stream>>>(x, emb, h);

  for (int l = 0; l < NL; ++l) {
    // ---- in_proj: xz = h @ W_in^T  (4096 x 3072, K=768) : 256^2 8-phase ----
    k_cvt<<<cdiv_l((long)BL * DM / 4, 256), 256, 0, stream>>>(h, abuf, (long)BL * DM / 4);
    k_cvt<<<cdiv_l((long)2 * DI * DM / 4, 256), 256, 0, stream>>>(
        W_in + (size_t)l * 2 * DI * DM, wbuf, (long)2 * DI * DM / 4);
    k_gemm256<0><<<(BL / 256) * (2 * DI / 256), 512, 0, stream>>>(
        abuf, wbuf, xz, nullptr, DM, 2 * DI, 2 * DI / 256);
    // ---- causal dw-conv + silu ----
    k_conv<<<cdiv_l((long)BL * DI, 256), 256, 0, stream>>>(
        xz, conv_w + (size_t)l * DI * DCONV, conv_b + (size_t)l * DI, uc, (long)BL * DI);
    // ---- x_proj: xdbl = uc @ W_x^T  (4096 x 80, K=1536; W padded to 128 rows) ----
    k_cvt<<<cdiv_l((long)BL * DI / 4, 256), 256, 0, stream>>>(uc, abuf, (long)BL * DI / 4);
    k_cvt_pad<<<cdiv_l(128L * DI, 256), 256, 0, stream>>>(
        W_x + (size_t)l * 80 * DI, wbuf, 80, DI, DI, DI, 128L * DI);
    k_gemm<0><<<dim3(1, BL / 128), 256, 0, stream>>>(
        abuf, wbuf, xdbl, nullptr, BL, 80, DI, 80);
    // ---- dt = softplus(dtlin @ W_dt^T + b_dt)  (K=48 padded to 64) ----
    k_cvt_pad<<<cdiv_l((long)BL * 64, 256), 256, 0, stream>>>(
        xdbl, abuf, BL, DTR, 80, 64, (long)BL * 64);
    k_cvt_pad<<<cdiv_l((long)DI * 64, 256), 256, 0, stream>>>(
        W_dt + (size_t)l * DI * DTR, wbuf, DI, DTR, DTR, 64, (long)DI * 64);
    k_gemm<3><<<dim3(DI / 128, BL / 128), 256, 0, stream>>>(
        abuf, wbuf, dtb, b_dt + (size_t)l * DI, BL, DI, 64, DI);
    // ---- chunked selective scan ----
    k_scan1<<<scan_blocks, 256, 0, stream>>>(dtb, uc, xdbl,
                                             A_log + (size_t)l * DI * DS, cA, cB);
    k_scan2<<<st_blocks, 256, 0, stream>>>(cA, cB, hst);
    k_scan3<<<scan_blocks, 256, 0, stream>>>(dtb, uc, xdbl,
                                             A_log + (size_t)l * DI * DS, hst, ysb);
    // ---- skip + gate -> bf16 ----
    k_gate<<<cdiv_l((long)BL * DI, 256), 256, 0, stream>>>(
        ysb, uc, xz, D_skip + (size_t)l * DI, abuf, (long)BL * DI);
    // ---- out_proj + residual: h += y @ W_out^T  (4096 x 768, K=1536) ----
    k_cvt<<<cdiv_l((long)DM * DI / 4, 256), 256, 0, stream>>>(
        W_out + (size_t)l * DM * DI, wbuf, (long)DM * DI / 4);
    k_gemm<2><<<dim3(DM / 128, BL / 128), 256, 0, stream>>>(
        abuf, wbuf, h, nullptr, BL, DM, DI, DM);
  }

  // ---- final LN -> bf16, head GEMM + bias : 256^2 8-phase ----
  k_ln<<<BL, 256, 0, stream>>>(h, ln_g, ln_b, abuf);
  k_cvt<<<cdiv_l((long)VOC * DM / 4, 256), 256, 0, stream>>>(head_w, wbuf, (long)VOC * DM / 4);
  k_gemm256<1><<<(BL / 256) * (VOC / 256), 512, 0, stream>>>(
      abuf, wbuf, out, head_b, DM, VOC, VOC / 256);
}